// Round 7
// baseline (2984.166 us; speedup 1.0000x reference)
//
#include <hip/hip_runtime.h>
#include <hip/hip_bf16.h>

// Sizes (fixed by the problem)
#define B_   64
#define T_   512
#define I_   512
#define H_   512
#define NTHR 256   // 4 waves; wave w owns units [U0+8w, U0+8w+8), all 16 rows

typedef short bf16x8 __attribute__((ext_vector_type(8)));
typedef float f32x4  __attribute__((ext_vector_type(4)));
typedef unsigned long long u64;
typedef unsigned short u16;

#define MFMA(a, b, c) __builtin_amdgcn_mfma_f32_16x16x32_bf16((a), (b), (c), 0, 0, 0)

__device__ __forceinline__ u16 f2b(float f) {
    __hip_bfloat16 h = __float2bfloat16(f);   // RNE
    return __builtin_bit_cast(u16, h);
}

// fast gate math (local path only): v_exp_f32 + v_rcp_f32
__device__ __forceinline__ float fsig(float x) {          // 1/(1+e^-x)
    float e = __builtin_amdgcn_exp2f(-1.442695040888963f * x);
    return __builtin_amdgcn_rcpf(1.f + e);
}
__device__ __forceinline__ float ftanh(float x) {         // 1 - 2/(e^{2x}+1)
    float e = __builtin_amdgcn_exp2f(2.885390081777927f * x);
    return 1.f - 2.f * __builtin_amdgcn_rcpf(e + 1.f);
}

// ---- agent-scope (LLC) ops: fallback path + consensus/verdict exchange ----
__device__ __forceinline__ u64 coh_ld64(const void* p) {
    return __hip_atomic_load((const u64*)p, __ATOMIC_RELAXED, __HIP_MEMORY_SCOPE_AGENT);
}
__device__ __forceinline__ void coh_st64(void* p, u64 v) {
    __hip_atomic_store((u64*)p, v, __ATOMIC_RELAXED, __HIP_MEMORY_SCOPE_AGENT);
}
__device__ __forceinline__ bool flag_ge(const int* f, int idx, int tgt) {
    return __hip_atomic_load(f + idx, __ATOMIC_RELAXED, __HIP_MEMORY_SCOPE_AGENT) >= tgt;
}

// ---- XCD-local (sc0 = L1-bypass, served by the XCD's shared L2) ----
__device__ __forceinline__ int sc0_ld_i32(const int* p) {
    int v;
    asm volatile("global_load_dword %0, %1, off sc0\n\ts_waitcnt vmcnt(0)"
                 : "=&v"(v) : "v"(p) : "memory");
    return v;
}
__device__ __forceinline__ void sc0_st_i32(int* p, int v) {
    asm volatile("global_store_dword %0, %1, off sc0" :: "v"(p), "v"(v) : "memory");
}
__device__ __forceinline__ void sc0_st128(void* p, bf16x8 v) {
    asm volatile("global_store_dwordx4 %0, %1, off sc0" :: "v"(p), "v"(v) : "memory");
}

// batched XCD-local fragment load: 16x dwordx4 sc0, waited inside (no rule-18 hazard)
#define GLD16(O, A)                                                         \
  asm volatile(                                                             \
    "global_load_dwordx4 %0, %16, off sc0\n\t"                              \
    "global_load_dwordx4 %1, %16, off offset:64 sc0\n\t"                    \
    "global_load_dwordx4 %2, %16, off offset:128 sc0\n\t"                   \
    "global_load_dwordx4 %3, %16, off offset:192 sc0\n\t"                   \
    "global_load_dwordx4 %4, %16, off offset:256 sc0\n\t"                   \
    "global_load_dwordx4 %5, %16, off offset:320 sc0\n\t"                   \
    "global_load_dwordx4 %6, %16, off offset:384 sc0\n\t"                   \
    "global_load_dwordx4 %7, %16, off offset:448 sc0\n\t"                   \
    "global_load_dwordx4 %8, %16, off offset:512 sc0\n\t"                   \
    "global_load_dwordx4 %9, %16, off offset:576 sc0\n\t"                   \
    "global_load_dwordx4 %10, %16, off offset:640 sc0\n\t"                  \
    "global_load_dwordx4 %11, %16, off offset:704 sc0\n\t"                  \
    "global_load_dwordx4 %12, %16, off offset:768 sc0\n\t"                  \
    "global_load_dwordx4 %13, %16, off offset:832 sc0\n\t"                  \
    "global_load_dwordx4 %14, %16, off offset:896 sc0\n\t"                  \
    "global_load_dwordx4 %15, %16, off offset:960 sc0\n\t"                  \
    "s_waitcnt vmcnt(0)"                                                    \
    : "=&v"(O[0]), "=&v"(O[1]), "=&v"(O[2]), "=&v"(O[3]),                   \
      "=&v"(O[4]), "=&v"(O[5]), "=&v"(O[6]), "=&v"(O[7]),                   \
      "=&v"(O[8]), "=&v"(O[9]), "=&v"(O[10]), "=&v"(O[11]),                 \
      "=&v"(O[12]), "=&v"(O[13]), "=&v"(O[14]), "=&v"(O[15])                \
    : "v"(A) : "memory")

// Agent publish (fallback): block tile from sc_all into [64][512] ring.
__device__ __forceinline__ void pub_agent(u16* ring, int* fp, int fval,
                                          const u16* sca, int lane, int R0, int U0) {
    const int r0 = lane >> 3, s0 = lane & 7;
    const int r1 = 8 + r0;
    u64 q0 = *(const u64*)(sca + r0 * 36 + s0 * 4);
    u64 q1 = *(const u64*)(sca + r1 * 36 + s0 * 4);
    coh_st64(ring + (size_t)(R0 + r0) * 512 + U0 + s0 * 4, q0);
    coh_st64(ring + (size_t)(R0 + r1) * 512 + U0 + s0 * 4, q1);
    asm volatile("s_waitcnt vmcnt(0)" ::: "memory");
    if (lane == 0)
        __hip_atomic_store(fp, fval, __ATOMIC_RELAXED, __HIP_MEMORY_SCOPE_AGENT);
}

// Init: x fp32 -> bf16; all 1408 control ints = -1. (h published in-kernel.)
__global__ void k_init(const float* __restrict__ x, u16* __restrict__ xb,
                       int* __restrict__ fl) {
    long i = (long)blockIdx.x * 256 + threadIdx.x;
    if (i < 2097152) {
        const float* p = x + i * 8;
        float4 a = *(const float4*)p;
        float4 b = *(const float4*)(p + 4);
        union { u16 s[8]; bf16x8 v; } u;
        u.s[0]=f2b(a.x); u.s[1]=f2b(a.y); u.s[2]=f2b(a.z); u.s[3]=f2b(a.w);
        u.s[4]=f2b(b.x); u.s[5]=f2b(b.y); u.s[6]=f2b(b.z); u.s[7]=f2b(b.w);
        *(bf16x8*)(xb + i * 8) = u.v;
    } else if (i < 2097152 + 1408) {
        fl[i - 2097152] = -1;
    }
}

__global__ __launch_bounds__(NTHR, 1) void k_lstm(
    const u16* __restrict__ xb,
    const float* __restrict__ Wx0, const float* __restrict__ Wh0, const float* __restrict__ b0,
    const float* __restrict__ Wx1, const float* __restrict__ Wh1, const float* __restrict__ b1,
    const float* __restrict__ c_in, const float* __restrict__ h_in,
    u16* __restrict__ h0ag, u16* __restrict__ h1ag,
    u16* __restrict__ h0loc, u16* __restrict__ h1loc,
    int* __restrict__ f0ag, int* __restrict__ f1ag,
    int* __restrict__ f0loc, int* __restrict__ f1loc,
    int* __restrict__ xcc_tab, int* __restrict__ probe, int* __restrict__ verd,
    float* __restrict__ out)
{
    const int bid = blockIdx.x;
    if ((bid & 7) >= 4) return;       // dummy blocks (XCD padding) exit
    const int g   = bid & 7;          // row group 0..3 -> target XCD g
    const int jj  = bid >> 3;         // 0..31
    const int lay = jj >> 4;          // 0/1
    const int u   = jj & 15;          // unit block: units [32u, 32u+32)
    const int tid  = threadIdx.x;
    const int wave = tid >> 6;
    const int lane = tid & 63;
    const int n    = lane & 15;
    const int quad = lane >> 4;
    const int R0   = g * 16;
    const int U0   = u * 32;

    __shared__ __align__(16) u16   hstage[2][8192];      // fallback staging
    __shared__ __align__(16) u16   sc_all[16 * 36];      // fallback publish tile
    __shared__ __align__(16) u16   swb [4][16][8];       // per-wave bf16 transpose
    __shared__ __align__(16) float sc_h[4][16][8];       // per-wave f32 scratch
    __shared__ int s_local;
    __shared__ int s_ver;

    // publish own XCC id (agent) for placement consensus
    int myxcc;
    asm volatile("s_getreg_b32 %0, hwreg(HW_REG_XCC_ID)" : "=s"(myxcc));
    if (tid == 0)
        __hip_atomic_store(xcc_tab + bid, myxcc, __ATOMIC_RELAXED, __HIP_MEMORY_SCOPE_AGENT);

    const float* Wx = lay ? Wx1 : Wx0;
    const float* Wh = lay ? Wh1 : Wh0;
    const float* bb = lay ? b1  : b0;
    const float bi = bb[0] + bb[1];
    const float bf = bb[2] + bb[3];
    const float bg = bb[4] + bb[5];
    const float bo = bb[6] + bb[7];

    // Full weight panel in registers (64 frags).
    // breg[ct][f]: lane holds B[k = f*32 + quad*8 + j][col = ct*16 + n]; k<512: Wx else Wh.
    bf16x8 breg[2][32];
    #pragma unroll
    for (int ct = 0; ct < 2; ++ct) {
        const int gate = ct * 2 + (n >> 3);            // 0:i 1:f 2:g 3:o
        const int gcol = gate * 512 + U0 + wave * 8 + (n & 7);
        #pragma unroll
        for (int f = 0; f < 32; ++f) {
            const int kbase = f * 32 + quad * 8;
            bf16x8 w;
            #pragma unroll
            for (int j = 0; j < 8; ++j) {
                const int k = kbase + j;
                const float v = (k < 512) ? Wx[(size_t)k * 2048 + gcol]
                                          : Wh[(size_t)(k - 512) * 2048 + gcol];
                w[j] = (short)f2b(v);
            }
            breg[ct][f] = w;
        }
    }

    // c-state in registers
    float creg[4];
    if (n < 8) {
        #pragma unroll
        for (int r = 0; r < 4; ++r)
            creg[r] = c_in[(size_t)lay * 32768
                           + (size_t)(R0 + quad * 4 + r) * 512 + U0 + wave * 8 + n];
    }

    // ---- stage 1: XCC consensus (are all 32 group members on one XCD?) ----
    if (wave == 0) {
        const int member = (lane & 31) * 8 + g;
        int v;
        for (;;) {
            v = __hip_atomic_load(xcc_tab + member, __ATOMIC_RELAXED, __HIP_MEMORY_SCOPE_AGENT);
            if (__all(v != -1)) break;
            __builtin_amdgcn_s_sleep(8);
        }
        const int v0 = __shfl(v, 0);
        if (lane == 0) s_local = __all(v == v0) ? 1 : 0;
    }
    __syncthreads();

    // ---- stage 2: bounded sc0 coherence probe (only if consensus passed) ----
    int myver = 0;
    if (s_local) {                       // block-uniform
        if (tid == 0) sc0_st_i32(probe + bid, 0x5a5a0000 | bid);
        if (wave == 0) {
            const int member = (lane & 31) * 8 + g;
            const int want = 0x5a5a0000 | member;
            int ok = 0;
            for (int it = 0; it < 4000 && !ok; ++it)
                ok = __all(sc0_ld_i32(probe + member) == want) ? 1 : 0;
            if (lane == 0) s_ver = ok;
        }
        __syncthreads();
        myver = s_ver;
    }

    // ---- stage 3: verdict exchange over the PROVEN agent path; AND-combine ----
    if (tid == 0)
        __hip_atomic_store(verd + bid, myver, __ATOMIC_RELAXED, __HIP_MEMORY_SCOPE_AGENT);
    if (wave == 0) {
        const int member = (lane & 31) * 8 + g;
        int v;
        for (;;) {
            v = __hip_atomic_load(verd + member, __ATOMIC_RELAXED, __HIP_MEMORY_SCOPE_AGENT);
            if (__all(v != -1)) break;
            __builtin_amdgcn_s_sleep(8);
        }
        if (lane == 0) s_local = __all(v == 1) ? 1 : 0;
    }
    __syncthreads();
    const bool loc = (s_local != 0);     // group-uniform by construction

    const int fidx = g * 16 + n;         // fallback poll index

    if (loc) {
        // =================== XCD-LOCAL PATH: 4 independent wave-agents ===================
        int* fl0 = f0loc + g * 64;                  // 64 per-wave flags (16 blocks x 4 waves)
        int* fl1 = f1loc + g * 64;
        int* myf = (lay ? fl1 : fl0) + u * 4 + wave;
        const int* p0 = fl0 + lane;                 // lane l polls wave-flag l
        const int* p1 = fl1 + lane;
        u16* ring  = (lay ? h1loc : h0loc) + (size_t)g * 65536;
        u16* ring0 = h0loc + (size_t)g * 65536;
        u16* ring1 = h1loc + (size_t)g * 65536;

        // prologue: per-wave publish of initial h as "step -1" (slot 7), flag = 0
        if (lane < 16) {
            const float* hp = h_in + (size_t)lay * 32768
                              + (size_t)(R0 + lane) * 512 + U0 + wave * 8;
            union { u16 s[8]; bf16x8 v; } pk;
            #pragma unroll
            for (int j = 0; j < 8; ++j) pk.s[j] = f2b(hp[j]);
            sc0_st128(ring + 7 * 8192 + lane * 512 + U0 + wave * 8, pk.v);
        }
        asm volatile("s_waitcnt vmcnt(0)" ::: "memory");
        if (lane == 0) sc0_st_i32(myf, 0);

        for (int t = 0; t < 512; ++t) {
            f32x4 acc0 = {0.f,0.f,0.f,0.f}, acc1 = {0.f,0.f,0.f,0.f};
            bf16x8 hf[16];

            if (lay == 0) {
                // x-phase (no cross dependency)
                const u16* px = xb + ((size_t)(R0 + n) * T_ + t) * I_;
                bf16x8 xa[16];
                #pragma unroll
                for (int f = 0; f < 16; ++f) xa[f] = *(const bf16x8*)(px + f * 32 + quad * 8);
                #pragma unroll
                for (int f = 0; f < 16; ++f) {
                    acc0 = MFMA(xa[f], breg[0][f], acc0);
                    acc1 = MFMA(xa[f], breg[1][f], acc1);
                }
                // ring WAR back-pressure (every 4th step, lag 4)
                if ((t & 3) == 0)
                    while (!__all(sc0_ld_i32(p1) >= t - 4)) {}
                // self-loop poll: peers' h0[t-1]
                while (!__all(sc0_ld_i32(p0) >= t)) {}
                GLD16(hf, ring0 + (size_t)((t - 1) & 7) * 8192 + n * 512 + quad * 8);
                #pragma unroll
                for (int f = 0; f < 16; ++f) {
                    acc0 = MFMA(hf[f], breg[0][16 + f], acc0);
                    acc1 = MFMA(hf[f], breg[1][16 + f], acc1);
                }
            } else {
                // h0 phase first: L0 runs ahead, this poll is usually instant
                while (!__all(sc0_ld_i32(p0) >= t + 1)) {}
                GLD16(hf, ring0 + (size_t)(t & 7) * 8192 + n * 512 + quad * 8);
                #pragma unroll
                for (int f = 0; f < 16; ++f) {
                    acc0 = MFMA(hf[f], breg[0][f], acc0);
                    acc1 = MFMA(hf[f], breg[1][f], acc1);
                }
                // binding self-loop: peers' h1[t-1]
                while (!__all(sc0_ld_i32(p1) >= t)) {}
                GLD16(hf, ring1 + (size_t)((t - 1) & 7) * 8192 + n * 512 + quad * 8);
                #pragma unroll
                for (int f = 0; f < 16; ++f) {
                    acc0 = MFMA(hf[f], breg[0][16 + f], acc0);
                    acc1 = MFMA(hf[f], breg[1][16 + f], acc1);
                }
            }

            // epilogue (fast gate math), per-wave transpose, per-wave publish
            f32x4 x0, x1;
            #pragma unroll
            for (int r = 0; r < 4; ++r) {
                x0[r] = __shfl_xor(acc0[r], 8);
                x1[r] = __shfl_xor(acc1[r], 8);
            }
            if (n < 8) {
                #pragma unroll
                for (int r = 0; r < 4; ++r) {
                    const int row = quad * 4 + r;
                    const float ig = fsig(acc0[r] + bi);
                    const float fg = fsig(x0[r]   + bf);
                    const float gg = ftanh(acc1[r] + bg);
                    const float og = fsig(x1[r]   + bo);
                    const float cn = fg * creg[r] + ig * gg;
                    const float hn = og * ftanh(cn);
                    creg[r] = cn;
                    swb [wave][row][n] = f2b(hn);
                    sc_h[wave][row][n] = hn;
                }
            }
            asm volatile("s_waitcnt lgkmcnt(0)" ::: "memory");
            __builtin_amdgcn_sched_barrier(0);
            if (lane < 16) {
                bf16x8 hv = *(const bf16x8*)&swb[wave][lane][0];
                sc0_st128(ring + (size_t)(t & 7) * 8192 + lane * 512 + U0 + wave * 8, hv);
            }
            asm volatile("s_waitcnt vmcnt(0)" ::: "memory");
            if (lane == 0) sc0_st_i32(myf, t + 1);

            // off-critical-path outputs
            if (lay && lane < 16) {
                const float* s = &sc_h[wave][lane][0];
                f32x4 a  = *(const f32x4*)s;
                f32x4 b2 = *(const f32x4*)(s + 4);
                float* po = out + ((size_t)(R0 + lane) * T_ + t) * H_ + U0 + wave * 8;
                *(f32x4*)po       = a;
                *(f32x4*)(po + 4) = b2;
            }
            if (t == 511 && n < 8) {
                const size_t o1 = (size_t)B_ * T_ * H_;
                #pragma unroll
                for (int r = 0; r < 4; ++r) {
                    const int grow = R0 + quad * 4 + r;
                    out[o1 + (size_t)lay * 32768 + (size_t)grow * 512 + U0 + wave * 8 + n]
                        = sc_h[wave][quad * 4 + r][n];
                    out[o1 + 65536 + (size_t)lay * 32768 + (size_t)grow * 512 + U0 + wave * 8 + n]
                        = creg[r];
                }
            }
        }
        return;
    }

    // =================== FALLBACK: agent path (R4, proven) ===================
    // prologue: publish initial h via sc_all (slot 7), flag = 0
    if (n < 8) {
        #pragma unroll
        for (int r = 0; r < 4; ++r) {
            const int row = quad * 4 + r;
            const float hv = h_in[(size_t)lay * 32768
                                  + (size_t)(R0 + row) * 512 + U0 + wave * 8 + n];
            sc_all[row * 36 + wave * 8 + n] = f2b(hv);
        }
    }
    __syncthreads();
    if (wave == 0)
        pub_agent((lay ? h1ag : h0ag) + (size_t)7 * 32768,
                  (lay ? f1ag : f0ag) + g * 16 + u, 0, sc_all, lane, R0, U0);

    for (int t = 0; t < 512; ++t) {
        f32x4 acc0 = {0.f,0.f,0.f,0.f}, acc1 = {0.f,0.f,0.f,0.f};
        if (lay == 0) {
            const u16* px = xb + ((size_t)(R0 + n) * T_ + t) * I_;
            bf16x8 xa[16];
            #pragma unroll
            for (int f = 0; f < 16; ++f) xa[f] = *(const bf16x8*)(px + f * 32 + quad * 8);
            #pragma unroll
            for (int f = 0; f < 16; ++f) {
                acc0 = MFMA(xa[f], breg[0][f], acc0);
                acc1 = MFMA(xa[f], breg[1][f], acc1);
            }
            const bool bp = (t & 3) == 0;
            for (;;) {
                bool ok = flag_ge(f0ag, fidx, t);
                if (bp) ok = ok && flag_ge(f1ag, fidx, t - 4);
                if (__all(ok)) break;
                __builtin_amdgcn_s_sleep(1);
            }
            asm volatile("" ::: "memory");
            const u16* base = h0ag + (size_t)((t - 1) & 7) * 32768;
            u64 v[8];
            #pragma unroll
            for (int i = 0; i < 8; ++i) {
                const int s = i * 256 + tid;
                const int r = s >> 7, m = s & 127;
                v[i] = coh_ld64(base + (size_t)(R0 + r) * 512 + m * 4);
            }
            #pragma unroll
            for (int i = 0; i < 8; ++i) {
                const int s = i * 256 + tid;
                const int r = s >> 7, m = s & 127;
                const int uu = m >> 1, sub = m & 1;
                *(u64*)&hstage[0][r * 512 + (((uu ^ (r & 7)) << 3) | (sub << 2))] = v[i];
            }
            __syncthreads();
            #pragma unroll
            for (int f = 0; f < 16; ++f) {
                bf16x8 ha = *(const bf16x8*)
                    &hstage[0][n * 512 + (((f * 4 + quad) ^ (n & 7)) << 3)];
                acc0 = MFMA(ha, breg[0][16 + f], acc0);
                acc1 = MFMA(ha, breg[1][16 + f], acc1);
            }
        } else {
            for (;;) {
                bool ok = flag_ge(f1ag, fidx, t) && flag_ge(f0ag, fidx, t + 1);
                if (__all(ok)) break;
                __builtin_amdgcn_s_sleep(1);
            }
            asm volatile("" ::: "memory");
            const u16* base0 = h0ag + (size_t)(t & 7) * 32768;
            const u16* base1 = h1ag + (size_t)((t - 1) & 7) * 32768;
            u64 v0[8], v1[8];
            #pragma unroll
            for (int i = 0; i < 8; ++i) {
                const int s = i * 256 + tid;
                const int r = s >> 7, m = s & 127;
                v0[i] = coh_ld64(base0 + (size_t)(R0 + r) * 512 + m * 4);
                v1[i] = coh_ld64(base1 + (size_t)(R0 + r) * 512 + m * 4);
            }
            #pragma unroll
            for (int i = 0; i < 8; ++i) {
                const int s = i * 256 + tid;
                const int r = s >> 7, m = s & 127;
                const int uu = m >> 1, sub = m & 1;
                const int off = r * 512 + (((uu ^ (r & 7)) << 3) | (sub << 2));
                *(u64*)&hstage[0][off] = v0[i];
                *(u64*)&hstage[1][off] = v1[i];
            }
            __syncthreads();
            #pragma unroll
            for (int f = 0; f < 16; ++f) {
                const int off = n * 512 + (((f * 4 + quad) ^ (n & 7)) << 3);
                bf16x8 ha = *(const bf16x8*)&hstage[0][off];
                acc0 = MFMA(ha, breg[0][f], acc0);
                acc1 = MFMA(ha, breg[1][f], acc1);
                bf16x8 hb = *(const bf16x8*)&hstage[1][off];
                acc0 = MFMA(hb, breg[0][16 + f], acc0);
                acc1 = MFMA(hb, breg[1][16 + f], acc1);
            }
        }
        f32x4 x0, x1;
        #pragma unroll
        for (int r = 0; r < 4; ++r) {
            x0[r] = __shfl_xor(acc0[r], 8);
            x1[r] = __shfl_xor(acc1[r], 8);
        }
        if (n < 8) {
            #pragma unroll
            for (int r = 0; r < 4; ++r) {
                const int row = quad * 4 + r;
                const float zi = acc0[r] + bi, zf = x0[r] + bf;
                const float zg = acc1[r] + bg, zo = x1[r] + bo;
                const float ig = 1.f / (1.f + __expf(-zi));
                const float fg = 1.f / (1.f + __expf(-zf));
                const float gg = tanhf(zg);
                const float og = 1.f / (1.f + __expf(-zo));
                const float cn = fg * creg[r] + ig * gg;
                const float hn = og * tanhf(cn);
                creg[r] = cn;
                sc_all[row * 36 + wave * 8 + n] = f2b(hn);
                sc_h[wave][row][n] = hn;
            }
        }
        __syncthreads();
        if (wave == 0)
            pub_agent((lay ? h1ag : h0ag) + (size_t)(t & 7) * 32768,
                      (lay ? f1ag : f0ag) + g * 16 + u, t + 1, sc_all, lane, R0, U0);
        if (lay && lane < 16) {
            const float* s = &sc_h[wave][lane][0];
            f32x4 a  = *(const f32x4*)s;
            f32x4 b2 = *(const f32x4*)(s + 4);
            float* po = out + ((size_t)(R0 + lane) * T_ + t) * H_ + U0 + wave * 8;
            *(f32x4*)po       = a;
            *(f32x4*)(po + 4) = b2;
        }
        if (t == 511 && n < 8) {
            const size_t o1 = (size_t)B_ * T_ * H_;
            #pragma unroll
            for (int r = 0; r < 4; ++r) {
                const int grow = R0 + quad * 4 + r;
                out[o1 + (size_t)lay * 32768 + (size_t)grow * 512 + U0 + wave * 8 + n]
                    = sc_h[wave][quad * 4 + r][n];
                out[o1 + 65536 + (size_t)lay * 32768 + (size_t)grow * 512 + U0 + wave * 8 + n]
                    = creg[r];
            }
        }
    }
}

extern "C" void kernel_launch(void* const* d_in, const int* in_sizes, int n_in,
                              void* d_out, int out_size, void* d_ws, size_t ws_size,
                              hipStream_t stream) {
    const float* x   = (const float*)d_in[0];
    const float* h   = (const float*)d_in[1];
    const float* c   = (const float*)d_in[2];
    const float* Wx0 = (const float*)d_in[3];
    const float* Wh0 = (const float*)d_in[4];
    const float* b0  = (const float*)d_in[5];
    const float* Wx1 = (const float*)d_in[6];
    const float* Wh1 = (const float*)d_in[7];
    const float* b1  = (const float*)d_in[8];
    float* out = (float*)d_out;

    // ws (~36 MB): xb, agent rings, local rings (4 groups x depth8 x 16 x 512),
    // then 1408 contiguous ints: f0ag|f1ag|f0loc|f1loc|xcc|probe|verd.
    u16* xb     = (u16*)d_ws;                 // 16,777,216 u16
    u16* h0ag   = xb + 16777216;              // 262144 u16
    u16* h1ag   = h0ag + 262144;              // 262144 u16
    u16* h0loc  = h1ag + 262144;              // 262144 u16
    u16* h1loc  = h0loc + 262144;             // 262144 u16
    int* f0ag   = (int*)(h1loc + 262144);     // 64
    int* f1ag   = f0ag + 64;                  // 64
    int* f0loc  = f1ag + 64;                  // 256 (4 groups x 64 wave-flags)
    int* f1loc  = f0loc + 256;                // 256
    int* xcc    = f1loc + 256;                // 256
    int* probe  = xcc + 256;                  // 256
    int* verd   = probe + 256;                // 256

    k_init<<<8198, 256, 0, stream>>>(x, xb, f0ag);
    k_lstm<<<256, NTHR, 0, stream>>>(xb, Wx0, Wh0, b0, Wx1, Wh1, b1, c, h,
                                     h0ag, h1ag, h0loc, h1loc,
                                     f0ag, f1ag, f0loc, f1loc, xcc, probe, verd, out);
}